// Round 7
// baseline (473.418 us; speedup 1.0000x reference)
//
#include <hip/hip_runtime.h>
#include <hip/hip_bf16.h>
#include <stdint.h>

// Problem constants
#define T_DIM 512
#define B_DIM 128
#define DIN   512
#define H_DIM 1024
#define M_DIM (T_DIM * B_DIM)          // 65536
#define OUT_ELEMS 67108864             // M_DIM * H_DIM

typedef __attribute__((ext_vector_type(8))) short bf16x8;
typedef __attribute__((ext_vector_type(4))) float f32x4;
typedef unsigned short u16;

static __device__ __forceinline__ u16 f2bf(float f) {
    union { float f; uint32_t u; } v; v.f = f;
    uint32_t u = v.u;
    uint32_t r = (u + 0x7FFFu + ((u >> 16) & 1u)) >> 16;   // RNE
    return (u16)r;
}

// hardware RNE cvt (compiler emits v_cvt_pk_bf16_f32 pairs; m240: scalar cast
// beats hand-written asm cvt_pk)
static __device__ __forceinline__ bf16x8 cvt8(float4 lo, float4 hi) {
    union { bf16x8 v; __hip_bfloat16 h[8]; } u;
    u.h[0] = __float2bfloat16(lo.x); u.h[1] = __float2bfloat16(lo.y);
    u.h[2] = __float2bfloat16(lo.z); u.h[3] = __float2bfloat16(lo.w);
    u.h[4] = __float2bfloat16(hi.x); u.h[5] = __float2bfloat16(hi.y);
    u.h[6] = __float2bfloat16(hi.z); u.h[7] = __float2bfloat16(hi.w);
    return u.v;
}

// ---------------------------------------------------------------------------
// Kernel 1 (tiny): convert W_in, W_h, hidden to bf16; copy hidden to out tail.
// Units of 8 elements: W_in [0,65536) W_h [65536,196608) hidden [196608,212992)
// ---------------------------------------------------------------------------
__global__ __launch_bounds__(256) void k_prep(
    const float* __restrict__ W_in, const float* __restrict__ W_h,
    const float* __restrict__ hidden,
    u16* __restrict__ Win_bf, u16* __restrict__ Wh_bf, u16* __restrict__ hid_bf,
    float* __restrict__ out_hidden)
{
    int u = blockIdx.x * 256 + threadIdx.x;
    const float* src; u16* dst; int i;
    if (u < 65536)       { i = u;          src = W_in;   dst = Win_bf; }
    else if (u < 196608) { i = u - 65536;  src = W_h;    dst = Wh_bf;  }
    else                 { i = u - 196608; src = hidden; dst = hid_bf; }
    float4 v0 = reinterpret_cast<const float4*>(src)[2 * (size_t)i];
    float4 v1 = reinterpret_cast<const float4*>(src)[2 * (size_t)i + 1];
    union { bf16x8 v; u16 s[8]; } r;
    r.s[0] = f2bf(v0.x); r.s[1] = f2bf(v0.y);
    r.s[2] = f2bf(v0.z); r.s[3] = f2bf(v0.w);
    r.s[4] = f2bf(v1.x); r.s[5] = f2bf(v1.y);
    r.s[6] = f2bf(v1.z); r.s[7] = f2bf(v1.w);
    reinterpret_cast<bf16x8*>(dst)[i] = r.v;
    if (u >= 196608) {    // second tuple output: hidden verbatim
        reinterpret_cast<float4*>(out_hidden)[2 * i]     = v0;
        reinterpret_cast<float4*>(out_hidden)[2 * i + 1] = v1;
    }
}

// ---------------------------------------------------------------------------
// Kernel 2: bias2[b][h] = hidden @ W_h^T + b_h + b_in   (128 x 1024, K=1024)
// ---------------------------------------------------------------------------
__global__ __launch_bounds__(256, 2) void k_bias2(
    const u16* __restrict__ hid_bf, const u16* __restrict__ Wh_bf,
    const float* __restrict__ b_in, const float* __restrict__ b_h,
    float* __restrict__ bias2)
{
    __shared__ alignas(16) char lds[16384];     // A: [0,8192) B: [8192,16384)
    const int tid = threadIdx.x;
    const int mt = blockIdx.x & 1, nt = blockIdx.x >> 1;   // 2 x 16 tiles
    const int m0 = mt * 64, n0 = nt * 64;
    const int l = tid & 63, w = tid >> 6;
    const int wm = w >> 1, wn = w & 1;
    const int r = l & 15, q = l >> 4;

    f32x4 acc[2][2] = {};

    for (int kb = 0; kb < 1024; kb += 64) {
        __syncthreads();
        #pragma unroll
        for (int i = 0; i < 2; ++i) {
            int idx = tid + i * 256;            // 0..511 : 64 rows x 8 chunks
            int row = idx >> 3, koff = (idx & 7) * 8;
            int off = (row * 128 + koff * 2) ^ ((row & 7) << 4);
            bf16x8 av = *reinterpret_cast<const bf16x8*>(&hid_bf[(m0 + row) * 1024 + kb + koff]);
            *reinterpret_cast<bf16x8*>(&lds[off]) = av;
            bf16x8 bv = *reinterpret_cast<const bf16x8*>(&Wh_bf[(n0 + row) * 1024 + kb + koff]);
            *reinterpret_cast<bf16x8*>(&lds[8192 + off]) = bv;
        }
        __syncthreads();
        #pragma unroll
        for (int kk = 0; kk < 2; ++kk) {
            bf16x8 a[2], b[2];
            #pragma unroll
            for (int mi = 0; mi < 2; ++mi) {
                int row = wm * 32 + mi * 16 + r;
                int off = (row * 128 + kk * 64 + q * 16) ^ ((row & 7) << 4);
                a[mi] = *reinterpret_cast<const bf16x8*>(&lds[off]);
            }
            #pragma unroll
            for (int ni = 0; ni < 2; ++ni) {
                int row = wn * 32 + ni * 16 + r;
                int off = 8192 + ((row * 128 + kk * 64 + q * 16) ^ ((row & 7) << 4));
                b[ni] = *reinterpret_cast<const bf16x8*>(&lds[off]);
            }
            #pragma unroll
            for (int mi = 0; mi < 2; ++mi)
                #pragma unroll
                for (int ni = 0; ni < 2; ++ni)
                    acc[mi][ni] = __builtin_amdgcn_mfma_f32_16x16x32_bf16(
                        a[mi], b[ni], acc[mi][ni], 0, 0, 0);
        }
    }
    #pragma unroll
    for (int mi = 0; mi < 2; ++mi)
        #pragma unroll
        for (int ni = 0; ni < 2; ++ni)
            #pragma unroll
            for (int reg = 0; reg < 4; ++reg) {
                int brow = m0 + wm * 32 + mi * 16 + q * 4 + reg;
                int col  = n0 + wn * 32 + ni * 16 + r;
                bias2[brow * 1024 + col] = acc[mi][ni][reg] + b_in[col] + b_h[col];
            }
}

// ---------------------------------------------------------------------------
// Kernel 3: main GEMM — NO LDS, NO BARRIERS. All fragments loaded directly
// from global (L1/L2-resident operands): W_in = 1 MB (L2 everywhere),
// x stripe = 256 KB f32 (XCD-L2 via swizzle). Each wave = independent
// dataflow pipeline with depth-1 prefetch; f32->bf16 cvt fused in-register.
//   Block 256 = 4 waves (2x2), block tile 128x128, wave tile 64x64,
//   4x4 16x16x32 frags, swapped-operand MFMA -> float4 epilogue.
//   Per kk (K=32): issue 12 loads for kk+1, 16 MFMA on kk, cvt next A.
// ---------------------------------------------------------------------------
__global__ __launch_bounds__(256, 2) void k_main(
    const float* __restrict__ x,          // [65536][512] f32
    const u16*   __restrict__ Win_bf,     // [1024][512] bf16
    const float* __restrict__ bias2,      // [128][1024]
    const float* __restrict__ hidden,     // [128][1024]
    float* __restrict__ out)              // [65536][1024]
{
    const int tid = threadIdx.x;
    const int bid = (int)blockIdx.x;
    // XCD-bijective swizzle: nwg=4096, 4096%8==0, cpx=512.
    // 8 consecutive wgids share one m-stripe (x L2 reuse within XCD).
    const int wgid = (bid & 7) * 512 + (bid >> 3);
    const int nt = wgid & 7, mt = wgid >> 3;
    const int m0 = mt * 128, n0 = nt * 128;
    const int l = tid & 63, w = tid >> 6;
    const int wm = w >> 1, wn = w & 1;          // 2x2 waves, 64x64 each
    const int r = l & 15, q = l >> 4;

    // per-lane fragment base pointers (frag mi/ni at +mi*16 rows, kk at +kk*32)
    const float* aptr = x      + (size_t)(m0 + wm * 64 + r) * 512 + q * 8;
    const u16*   bptr = Win_bf + (size_t)(n0 + wn * 64 + r) * 512 + q * 8;

    f32x4 acc[4][4] = {};

    bf16x8 acur[4], bcur[4], bnxt[4];
    float4 af0[4], af1[4];

    // -------- prologue: kk=0 --------
    #pragma unroll
    for (int mi = 0; mi < 4; ++mi) {
        const float* s = aptr + (size_t)mi * 8192;
        af0[mi] = *reinterpret_cast<const float4*>(s);
        af1[mi] = *reinterpret_cast<const float4*>(s + 4);
        bcur[mi] = *reinterpret_cast<const bf16x8*>(bptr + (size_t)mi * 8192);
    }
    #pragma unroll
    for (int mi = 0; mi < 4; ++mi)
        acur[mi] = cvt8(af0[mi], af1[mi]);

    // -------- main loop: 16 kk-steps of K=32, no sync anywhere --------
    #pragma unroll
    for (int kk = 0; kk < 16; ++kk) {
        // issue next step's loads (hidden under this step's MFMAs)
        if (kk < 15) {
            #pragma unroll
            for (int mi = 0; mi < 4; ++mi) {
                const float* s = aptr + (size_t)mi * 8192 + (kk + 1) * 32;
                af0[mi] = *reinterpret_cast<const float4*>(s);
                af1[mi] = *reinterpret_cast<const float4*>(s + 4);
                bnxt[mi] = *reinterpret_cast<const bf16x8*>(
                    bptr + (size_t)mi * 8192 + (kk + 1) * 32);
            }
        }
        // 16 MFMA on current frags (swapped operands)
        #pragma unroll
        for (int mi = 0; mi < 4; ++mi)
            #pragma unroll
            for (int ni = 0; ni < 4; ++ni)
                acc[mi][ni] = __builtin_amdgcn_mfma_f32_16x16x32_bf16(
                    bcur[ni], acur[mi], acc[mi][ni], 0, 0, 0);
        // rotate pipeline: convert A(kk+1), swap B
        if (kk < 15) {
            #pragma unroll
            for (int mi = 0; mi < 4; ++mi) {
                acur[mi] = cvt8(af0[mi], af1[mi]);
                bcur[mi] = bnxt[mi];
            }
        }
    }

    // ---- epilogue: out = 0.9*hidden + 0.1*relu(acc + bias2), float4-wide ----
    #pragma unroll
    for (int mi = 0; mi < 4; ++mi) {
        const int m = m0 + wm * 64 + mi * 16 + r;
        const int b = m & 127;                  // m = t*128 + b
        #pragma unroll
        for (int ni = 0; ni < 4; ++ni) {
            const int n = n0 + wn * 64 + ni * 16 + q * 4;
            float4 bb = *reinterpret_cast<const float4*>(&bias2[b * 1024 + n]);
            float4 hh = *reinterpret_cast<const float4*>(&hidden[b * 1024 + n]);
            f32x4 v = acc[mi][ni];
            float4 o;
            o.x = 0.9f * hh.x + 0.1f * fmaxf(v[0] + bb.x, 0.0f);
            o.y = 0.9f * hh.y + 0.1f * fmaxf(v[1] + bb.y, 0.0f);
            o.z = 0.9f * hh.z + 0.1f * fmaxf(v[2] + bb.z, 0.0f);
            o.w = 0.9f * hh.w + 0.1f * fmaxf(v[3] + bb.w, 0.0f);
            *reinterpret_cast<float4*>(&out[(size_t)m * 1024 + n]) = o;
        }
    }
}

// ---------------------------------------------------------------------------
extern "C" void kernel_launch(void* const* d_in, const int* in_sizes, int n_in,
                              void* d_out, int out_size, void* d_ws, size_t ws_size,
                              hipStream_t stream) {
    const float* x      = (const float*)d_in[0];
    const float* hidden = (const float*)d_in[1];
    const float* W_in   = (const float*)d_in[2];
    const float* b_in   = (const float*)d_in[3];
    const float* W_h    = (const float*)d_in[4];
    const float* b_h    = (const float*)d_in[5];
    float* out = (float*)d_out;

    char* ws = (char*)d_ws;                    // ~4 MiB scratch
    u16*   Win_bf = (u16*)  (ws + 0);          // 1 MiB
    u16*   Wh_bf  = (u16*)  (ws + 1048576);    // 2 MiB
    u16*   hid_bf = (u16*)  (ws + 3145728);    // 256 KiB
    float* bias2  = (float*)(ws + 3407872);    // 512 KiB

    float* out_hidden = out + OUT_ELEMS;       // tuple output 1: hidden

    k_prep<<<832, 256, 0, stream>>>(W_in, W_h, hidden,
                                    Win_bf, Wh_bf, hid_bf, out_hidden);
    k_bias2<<<32, 256, 0, stream>>>(hid_bf, Wh_bf, b_in, b_h, bias2);
    k_main<<<4096, 256, 0, stream>>>(x, Win_bf, bias2, hidden, out);
}

// Round 8
// 262.792 us; speedup vs baseline: 1.8015x; 1.8015x over previous
//
#include <hip/hip_runtime.h>
#include <stdint.h>

// Problem constants
#define T_DIM 512
#define B_DIM 128
#define DIN   512
#define H_DIM 1024
#define M_DIM (T_DIM * B_DIM)          // 65536
#define OUT_ELEMS 67108864             // M_DIM * H_DIM

typedef __attribute__((ext_vector_type(8))) short bf16x8;
typedef __attribute__((ext_vector_type(4))) float f32x4;
typedef unsigned short u16;

static __device__ __forceinline__ u16 f2bf(float f) {
    union { float f; uint32_t u; } v; v.f = f;
    uint32_t u = v.u;
    uint32_t r = (u + 0x7FFFu + ((u >> 16) & 1u)) >> 16;   // RNE
    return (u16)r;
}

static __device__ __forceinline__ bf16x8 pack8(float4 v0, float4 v1) {
    union { bf16x8 v; u16 s[8]; } r;
    r.s[0] = f2bf(v0.x); r.s[1] = f2bf(v0.y);
    r.s[2] = f2bf(v0.z); r.s[3] = f2bf(v0.w);
    r.s[4] = f2bf(v1.x); r.s[5] = f2bf(v1.y);
    r.s[6] = f2bf(v1.z); r.s[7] = f2bf(v1.w);
    return r.v;
}

// ---------------------------------------------------------------------------
// Fragment layout (per 16 rows x 512 k):  frag[m16][kk][lane][8]
//   lane = q*16 + r ; element (row = m16*16 + r, k = kk*32 + q*8 + e)
// This is EXACTLY the per-lane A/B register layout of mfma_16x16x32_bf16,
// so k_main loads are wave-contiguous 1 KB (perfect coalescing, no LDS).
// ---------------------------------------------------------------------------

// Kernel 0: x (f32) -> x_frag (bf16, fragment-ordered). 1 unit = 8 elems.
__global__ __launch_bounds__(256) void k_convert(
    const float* __restrict__ x, u16* __restrict__ x_frag)
{
    int u = blockIdx.x * 256 + threadIdx.x;      // 0 .. 4194303
    int r = u & 15, q = (u >> 4) & 3, kk = (u >> 6) & 15, m16 = u >> 10;
    const float* s = x + (size_t)(m16 * 16 + r) * 512 + kk * 32 + q * 8;
    float4 v0 = *reinterpret_cast<const float4*>(s);
    float4 v1 = *reinterpret_cast<const float4*>(s + 4);
    // dst: perfectly coalesced (wave writes 1 KB contiguous)
    reinterpret_cast<bf16x8*>(x_frag)[u] = pack8(v0, v1);
}

// Kernel 1: W_in -> frag layout; W_h, hidden -> linear bf16; hidden -> out tail
// units: W_in [0,65536) W_h [65536,196608) hidden [196608,212992)
__global__ __launch_bounds__(256) void k_prep(
    const float* __restrict__ W_in, const float* __restrict__ W_h,
    const float* __restrict__ hidden,
    u16* __restrict__ Win_frag, u16* __restrict__ Wh_bf, u16* __restrict__ hid_bf,
    float* __restrict__ out_hidden)
{
    int u = blockIdx.x * 256 + threadIdx.x;
    if (u < 65536) {                              // W_in -> fragment order
        int r = u & 15, q = (u >> 4) & 3, kk = (u >> 6) & 15, n16 = u >> 10;
        const float* s = W_in + (size_t)(n16 * 16 + r) * 512 + kk * 32 + q * 8;
        float4 v0 = *reinterpret_cast<const float4*>(s);
        float4 v1 = *reinterpret_cast<const float4*>(s + 4);
        reinterpret_cast<bf16x8*>(Win_frag)[u] = pack8(v0, v1);
    } else if (u < 196608) {                      // W_h -> linear bf16
        int i = u - 65536;
        float4 v0 = reinterpret_cast<const float4*>(W_h)[2 * (size_t)i];
        float4 v1 = reinterpret_cast<const float4*>(W_h)[2 * (size_t)i + 1];
        reinterpret_cast<bf16x8*>(Wh_bf)[i] = pack8(v0, v1);
    } else {                                      // hidden -> bf16 + copy out
        int i = u - 196608;
        float4 v0 = reinterpret_cast<const float4*>(hidden)[2 * (size_t)i];
        float4 v1 = reinterpret_cast<const float4*>(hidden)[2 * (size_t)i + 1];
        reinterpret_cast<bf16x8*>(hid_bf)[i] = pack8(v0, v1);
        reinterpret_cast<float4*>(out_hidden)[2 * i]     = v0;
        reinterpret_cast<float4*>(out_hidden)[2 * i + 1] = v1;
    }
}

// ---------------------------------------------------------------------------
// Kernel 2: bias2[b][h] = hidden @ W_h^T + b_h + b_in   (128 x 1024, K=1024)
// ---------------------------------------------------------------------------
__global__ __launch_bounds__(256, 2) void k_bias2(
    const u16* __restrict__ hid_bf, const u16* __restrict__ Wh_bf,
    const float* __restrict__ b_in, const float* __restrict__ b_h,
    float* __restrict__ bias2)
{
    __shared__ alignas(16) char lds[16384];     // A: [0,8192) B: [8192,16384)
    const int tid = threadIdx.x;
    const int mt = blockIdx.x & 1, nt = blockIdx.x >> 1;   // 2 x 16 tiles
    const int m0 = mt * 64, n0 = nt * 64;
    const int l = tid & 63, w = tid >> 6;
    const int wm = w >> 1, wn = w & 1;
    const int r = l & 15, q = l >> 4;

    f32x4 acc[2][2] = {};

    for (int kb = 0; kb < 1024; kb += 64) {
        __syncthreads();
        #pragma unroll
        for (int i = 0; i < 2; ++i) {
            int idx = tid + i * 256;            // 0..511 : 64 rows x 8 chunks
            int row = idx >> 3, koff = (idx & 7) * 8;
            int off = (row * 128 + koff * 2) ^ ((row & 7) << 4);
            bf16x8 av = *reinterpret_cast<const bf16x8*>(&hid_bf[(m0 + row) * 1024 + kb + koff]);
            *reinterpret_cast<bf16x8*>(&lds[off]) = av;
            bf16x8 bv = *reinterpret_cast<const bf16x8*>(&Wh_bf[(n0 + row) * 1024 + kb + koff]);
            *reinterpret_cast<bf16x8*>(&lds[8192 + off]) = bv;
        }
        __syncthreads();
        #pragma unroll
        for (int kk = 0; kk < 2; ++kk) {
            bf16x8 a[2], b[2];
            #pragma unroll
            for (int mi = 0; mi < 2; ++mi) {
                int row = wm * 32 + mi * 16 + r;
                int off = (row * 128 + kk * 64 + q * 16) ^ ((row & 7) << 4);
                a[mi] = *reinterpret_cast<const bf16x8*>(&lds[off]);
            }
            #pragma unroll
            for (int ni = 0; ni < 2; ++ni) {
                int row = wn * 32 + ni * 16 + r;
                int off = 8192 + ((row * 128 + kk * 64 + q * 16) ^ ((row & 7) << 4));
                b[ni] = *reinterpret_cast<const bf16x8*>(&lds[off]);
            }
            #pragma unroll
            for (int mi = 0; mi < 2; ++mi)
                #pragma unroll
                for (int ni = 0; ni < 2; ++ni)
                    acc[mi][ni] = __builtin_amdgcn_mfma_f32_16x16x32_bf16(
                        a[mi], b[ni], acc[mi][ni], 0, 0, 0);
        }
    }
    #pragma unroll
    for (int mi = 0; mi < 2; ++mi)
        #pragma unroll
        for (int ni = 0; ni < 2; ++ni)
            #pragma unroll
            for (int reg = 0; reg < 4; ++reg) {
                int brow = m0 + wm * 32 + mi * 16 + q * 4 + reg;
                int col  = n0 + wn * 32 + ni * 16 + r;
                bias2[brow * 1024 + col] = acc[mi][ni][reg] + b_in[col] + b_h[col];
            }
}

// ---------------------------------------------------------------------------
// Kernel 3: main GEMM — fragment-ordered operands, NO LDS, NO BARRIERS.
//   Every A/B load is wave-contiguous 1 KB (lane*16B) from L2/L3-resident
//   frag arrays. Each wave = independent dataflow pipeline, depth-2 rotation.
//   Block 256 = 4 waves (2x2), block tile 128x128, wave tile 64x64.
//   Swapped-operand MFMA -> float4 epilogue.
// ---------------------------------------------------------------------------
__global__ __launch_bounds__(256, 3) void k_main(
    const u16* __restrict__ x_frag,       // [4096][16][64][8] bf16
    const u16* __restrict__ Win_frag,     // [64][16][64][8] bf16
    const float* __restrict__ bias2,      // [128][1024]
    const float* __restrict__ hidden,     // [128][1024]
    float* __restrict__ out)              // [65536][1024]
{
    const int tid = threadIdx.x;
    const int bid = (int)blockIdx.x;
    // XCD-bijective swizzle: nwg=4096, cpx=512. 8 consecutive wgids share
    // one A m-stripe (XCD-L2 reuse).
    const int wgid = (bid & 7) * 512 + (bid >> 3);
    const int nt = wgid & 7, mt = wgid >> 3;
    const int m0 = mt * 128, n0 = nt * 128;
    const int l = tid & 63, w = tid >> 6;
    const int wm = w >> 1, wn = w & 1;          // 2x2 waves, 64x64 each
    const int r = l & 15, q = l >> 4;

    // fragment bases: frag (mi, kk) at + mi*8192 + kk*512 elements
    const u16* abase = x_frag   + (size_t)(m0 / 16 + wm * 4) * 8192 + l * 8;
    const u16* bbase = Win_frag + (size_t)(n0 / 16 + wn * 4) * 8192 + l * 8;

    f32x4 acc[4][4] = {};
    bf16x8 a0[4], b0[4], a1[4], b1[4];

    #pragma unroll
    for (int i = 0; i < 4; ++i) {
        a0[i] = *reinterpret_cast<const bf16x8*>(abase + i * 8192);
        b0[i] = *reinterpret_cast<const bf16x8*>(bbase + i * 8192);
        a1[i] = *reinterpret_cast<const bf16x8*>(abase + i * 8192 + 512);
        b1[i] = *reinterpret_cast<const bf16x8*>(bbase + i * 8192 + 512);
    }

    // 16 kk-steps (K=32 each), two per iteration, no sync anywhere
    #pragma unroll
    for (int t = 0; t < 8; ++t) {
        #pragma unroll
        for (int mi = 0; mi < 4; ++mi)
            #pragma unroll
            for (int ni = 0; ni < 4; ++ni)
                acc[mi][ni] = __builtin_amdgcn_mfma_f32_16x16x32_bf16(
                    b0[ni], a0[mi], acc[mi][ni], 0, 0, 0);
        if (t < 7) {
            #pragma unroll
            for (int i = 0; i < 4; ++i) {
                a0[i] = *reinterpret_cast<const bf16x8*>(abase + i * 8192 + (2 * t + 2) * 512);
                b0[i] = *reinterpret_cast<const bf16x8*>(bbase + i * 8192 + (2 * t + 2) * 512);
            }
        }
        #pragma unroll
        for (int mi = 0; mi < 4; ++mi)
            #pragma unroll
            for (int ni = 0; ni < 4; ++ni)
                acc[mi][ni] = __builtin_amdgcn_mfma_f32_16x16x32_bf16(
                    b1[ni], a1[mi], acc[mi][ni], 0, 0, 0);
        if (t < 7) {
            #pragma unroll
            for (int i = 0; i < 4; ++i) {
                a1[i] = *reinterpret_cast<const bf16x8*>(abase + i * 8192 + (2 * t + 3) * 512);
                b1[i] = *reinterpret_cast<const bf16x8*>(bbase + i * 8192 + (2 * t + 3) * 512);
            }
        }
    }

    // ---- epilogue: out = 0.9*hidden + 0.1*relu(acc + bias2), float4-wide ----
    #pragma unroll
    for (int mi = 0; mi < 4; ++mi) {
        const int m = m0 + wm * 64 + mi * 16 + r;
        const int b = m & 127;                  // m = t*128 + b
        #pragma unroll
        for (int ni = 0; ni < 4; ++ni) {
            const int n = n0 + wn * 64 + ni * 16 + q * 4;
            float4 bb = *reinterpret_cast<const float4*>(&bias2[b * 1024 + n]);
            float4 hh = *reinterpret_cast<const float4*>(&hidden[b * 1024 + n]);
            f32x4 v = acc[mi][ni];
            float4 o;
            o.x = 0.9f * hh.x + 0.1f * fmaxf(v[0] + bb.x, 0.0f);
            o.y = 0.9f * hh.y + 0.1f * fmaxf(v[1] + bb.y, 0.0f);
            o.z = 0.9f * hh.z + 0.1f * fmaxf(v[2] + bb.z, 0.0f);
            o.w = 0.9f * hh.w + 0.1f * fmaxf(v[3] + bb.w, 0.0f);
            *reinterpret_cast<float4*>(&out[(size_t)m * 1024 + n]) = o;
        }
    }
}

// ---------------------------------------------------------------------------
extern "C" void kernel_launch(void* const* d_in, const int* in_sizes, int n_in,
                              void* d_out, int out_size, void* d_ws, size_t ws_size,
                              hipStream_t stream) {
    const float* x      = (const float*)d_in[0];
    const float* hidden = (const float*)d_in[1];
    const float* W_in   = (const float*)d_in[2];
    const float* b_in   = (const float*)d_in[3];
    const float* W_h    = (const float*)d_in[4];
    const float* b_h    = (const float*)d_in[5];
    float* out = (float*)d_out;

    char* ws = (char*)d_ws;                    // ~68 MiB scratch
    u16*   x_frag   = (u16*)  (ws + 0);        // 64 MiB
    u16*   Win_frag = (u16*)  (ws + 67108864); // 1 MiB
    u16*   Wh_bf    = (u16*)  (ws + 68157440); // 2 MiB
    u16*   hid_bf   = (u16*)  (ws + 70254592); // 256 KiB
    float* bias2    = (float*)(ws + 70516736); // 512 KiB

    float* out_hidden = out + OUT_ELEMS;       // tuple output 1: hidden

    k_convert<<<16384, 256, 0, stream>>>(x, x_frag);
    k_prep<<<832, 256, 0, stream>>>(W_in, W_h, hidden,
                                    Win_frag, Wh_bf, hid_bf, out_hidden);
    k_bias2<<<32, 256, 0, stream>>>(hid_bf, Wh_bf, b_in, b_h, bias2);
    k_main<<<4096, 256, 0, stream>>>(x_frag, Win_frag, bias2, hidden, out);
}

// Round 9
// 228.190 us; speedup vs baseline: 2.0747x; 1.1516x over previous
//
#include <hip/hip_runtime.h>
#include <stdint.h>

// Problem constants
#define T_DIM 512
#define B_DIM 128
#define DIN   512
#define H_DIM 1024
#define M_DIM (T_DIM * B_DIM)          // 65536
#define OUT_ELEMS 67108864             // M_DIM * H_DIM

typedef __attribute__((ext_vector_type(8))) short bf16x8;
typedef __attribute__((ext_vector_type(4))) float f32x4;
typedef unsigned short u16;

static __device__ __forceinline__ u16 f2bf(float f) {
    union { float f; uint32_t u; } v; v.f = f;
    uint32_t u = v.u;
    uint32_t r = (u + 0x7FFFu + ((u >> 16) & 1u)) >> 16;   // RNE
    return (u16)r;
}

static __device__ __forceinline__ bf16x8 pack8(float4 v0, float4 v1) {
    union { bf16x8 v; u16 s[8]; } r;
    r.s[0] = f2bf(v0.x); r.s[1] = f2bf(v0.y);
    r.s[2] = f2bf(v0.z); r.s[3] = f2bf(v0.w);
    r.s[4] = f2bf(v1.x); r.s[5] = f2bf(v1.y);
    r.s[6] = f2bf(v1.z); r.s[7] = f2bf(v1.w);
    return r.v;
}

// ---------------------------------------------------------------------------
// Fragment layout (per 16 rows x 512 k):  frag[m16][kk][lane][8]
//   lane = q*16 + r ; element (row = m16*16 + r, k = kk*32 + q*8 + e)
// Exactly the per-lane A/B register layout of mfma_16x16x32_bf16 ->
// k_main loads are wave-contiguous 1 KB.
// ---------------------------------------------------------------------------

// Kernel 0: x (f32) -> x_frag (bf16, fragment-ordered). 1 unit = 8 elems.
__global__ __launch_bounds__(256) void k_convert(
    const float* __restrict__ x, u16* __restrict__ x_frag)
{
    int u = blockIdx.x * 256 + threadIdx.x;      // 0 .. 4194303
    int r = u & 15, q = (u >> 4) & 3, kk = (u >> 6) & 15, m16 = u >> 10;
    const float* s = x + (size_t)(m16 * 16 + r) * 512 + kk * 32 + q * 8;
    float4 v0 = *reinterpret_cast<const float4*>(s);
    float4 v1 = *reinterpret_cast<const float4*>(s + 4);
    reinterpret_cast<bf16x8*>(x_frag)[u] = pack8(v0, v1);
}

// Kernel 1: W_in -> frag layout; W_h, hidden -> linear bf16; hidden -> out tail
__global__ __launch_bounds__(256) void k_prep(
    const float* __restrict__ W_in, const float* __restrict__ W_h,
    const float* __restrict__ hidden,
    u16* __restrict__ Win_frag, u16* __restrict__ Wh_bf, u16* __restrict__ hid_bf,
    float* __restrict__ out_hidden)
{
    int u = blockIdx.x * 256 + threadIdx.x;
    if (u < 65536) {                              // W_in -> fragment order
        int r = u & 15, q = (u >> 4) & 3, kk = (u >> 6) & 15, n16 = u >> 10;
        const float* s = W_in + (size_t)(n16 * 16 + r) * 512 + kk * 32 + q * 8;
        float4 v0 = *reinterpret_cast<const float4*>(s);
        float4 v1 = *reinterpret_cast<const float4*>(s + 4);
        reinterpret_cast<bf16x8*>(Win_frag)[u] = pack8(v0, v1);
    } else if (u < 196608) {                      // W_h -> linear bf16
        int i = u - 65536;
        float4 v0 = reinterpret_cast<const float4*>(W_h)[2 * (size_t)i];
        float4 v1 = reinterpret_cast<const float4*>(W_h)[2 * (size_t)i + 1];
        reinterpret_cast<bf16x8*>(Wh_bf)[i] = pack8(v0, v1);
    } else {                                      // hidden -> bf16 + copy out
        int i = u - 196608;
        float4 v0 = reinterpret_cast<const float4*>(hidden)[2 * (size_t)i];
        float4 v1 = reinterpret_cast<const float4*>(hidden)[2 * (size_t)i + 1];
        reinterpret_cast<bf16x8*>(hid_bf)[i] = pack8(v0, v1);
        reinterpret_cast<float4*>(out_hidden)[2 * i]     = v0;
        reinterpret_cast<float4*>(out_hidden)[2 * i + 1] = v1;
    }
}

// ---------------------------------------------------------------------------
// Kernel 2: bias2[b][h] = hidden @ W_h^T + b_h + b_in   (128 x 1024, K=1024)
// ---------------------------------------------------------------------------
__global__ __launch_bounds__(256, 2) void k_bias2(
    const u16* __restrict__ hid_bf, const u16* __restrict__ Wh_bf,
    const float* __restrict__ b_in, const float* __restrict__ b_h,
    float* __restrict__ bias2)
{
    __shared__ alignas(16) char lds[16384];     // A: [0,8192) B: [8192,16384)
    const int tid = threadIdx.x;
    const int mt = blockIdx.x & 1, nt = blockIdx.x >> 1;   // 2 x 16 tiles
    const int m0 = mt * 64, n0 = nt * 64;
    const int l = tid & 63, w = tid >> 6;
    const int wm = w >> 1, wn = w & 1;
    const int r = l & 15, q = l >> 4;

    f32x4 acc[2][2] = {};

    for (int kb = 0; kb < 1024; kb += 64) {
        __syncthreads();
        #pragma unroll
        for (int i = 0; i < 2; ++i) {
            int idx = tid + i * 256;            // 0..511 : 64 rows x 8 chunks
            int row = idx >> 3, koff = (idx & 7) * 8;
            int off = (row * 128 + koff * 2) ^ ((row & 7) << 4);
            bf16x8 av = *reinterpret_cast<const bf16x8*>(&hid_bf[(m0 + row) * 1024 + kb + koff]);
            *reinterpret_cast<bf16x8*>(&lds[off]) = av;
            bf16x8 bv = *reinterpret_cast<const bf16x8*>(&Wh_bf[(n0 + row) * 1024 + kb + koff]);
            *reinterpret_cast<bf16x8*>(&lds[8192 + off]) = bv;
        }
        __syncthreads();
        #pragma unroll
        for (int kk = 0; kk < 2; ++kk) {
            bf16x8 a[2], b[2];
            #pragma unroll
            for (int mi = 0; mi < 2; ++mi) {
                int row = wm * 32 + mi * 16 + r;
                int off = (row * 128 + kk * 64 + q * 16) ^ ((row & 7) << 4);
                a[mi] = *reinterpret_cast<const bf16x8*>(&lds[off]);
            }
            #pragma unroll
            for (int ni = 0; ni < 2; ++ni) {
                int row = wn * 32 + ni * 16 + r;
                int off = 8192 + ((row * 128 + kk * 64 + q * 16) ^ ((row & 7) << 4));
                b[ni] = *reinterpret_cast<const bf16x8*>(&lds[off]);
            }
            #pragma unroll
            for (int mi = 0; mi < 2; ++mi)
                #pragma unroll
                for (int ni = 0; ni < 2; ++ni)
                    acc[mi][ni] = __builtin_amdgcn_mfma_f32_16x16x32_bf16(
                        a[mi], b[ni], acc[mi][ni], 0, 0, 0);
        }
    }
    #pragma unroll
    for (int mi = 0; mi < 2; ++mi)
        #pragma unroll
        for (int ni = 0; ni < 2; ++ni)
            #pragma unroll
            for (int reg = 0; reg < 4; ++reg) {
                int brow = m0 + wm * 32 + mi * 16 + q * 4 + reg;
                int col  = n0 + wn * 32 + ni * 16 + r;
                bias2[brow * 1024 + col] = acc[mi][ni][reg] + b_in[col] + b_h[col];
            }
}

// ---------------------------------------------------------------------------
// Kernel 3: main GEMM — fragment-ordered, NO LDS/barriers, asm-pinned
// depth-4 register pipeline with counted vmcnt (never 0 in steady state).
//   Step t: s_waitcnt vmcnt(24) [set t landed, 24 in flight]
//           -> 16 MFMA on set (t%4)  -> issue 8 loads for t+4 into set (t%4)
// ---------------------------------------------------------------------------

// asm load: 16B wave-contiguous; address computed by compiler per literal T
#define LDF(dst, ptr, T) \
    asm volatile("global_load_dwordx4 %0, %1, off" \
                 : "=v"(dst) : "v"((ptr) + (T) * 512));

#define LD8(S, T) do { \
    LDF(A##S[0], pa0, T) LDF(A##S[1], pa1, T) LDF(A##S[2], pa2, T) LDF(A##S[3], pa3, T) \
    LDF(B##S[0], pb0, T) LDF(B##S[1], pb1, T) LDF(B##S[2], pb2, T) LDF(B##S[3], pb3, T) \
} while (0)

#define MFMA16(S) do { \
    _Pragma("unroll") \
    for (int mi = 0; mi < 4; ++mi) { \
        _Pragma("unroll") \
        for (int ni = 0; ni < 4; ++ni) \
            acc[mi][ni] = __builtin_amdgcn_mfma_f32_16x16x32_bf16( \
                B##S[ni], A##S[mi], acc[mi][ni], 0, 0, 0); \
    } \
} while (0)

#define STEP(T, S, WAITN) do { \
    asm volatile("s_waitcnt vmcnt(" #WAITN ")" ::: "memory"); \
    __builtin_amdgcn_sched_barrier(0); \
    __builtin_amdgcn_s_setprio(1); \
    MFMA16(S); \
    __builtin_amdgcn_s_setprio(0); \
    __builtin_amdgcn_sched_barrier(0); \
    if ((T) + 4 < 16) { LD8(S, (T) + 4); } \
    __builtin_amdgcn_sched_barrier(0); \
} while (0)

__global__ __launch_bounds__(256, 2) void k_main(
    const u16* __restrict__ x_frag,       // [4096][16][64][8] bf16
    const u16* __restrict__ Win_frag,     // [64][16][64][8] bf16
    const float* __restrict__ bias2,      // [128][1024]
    const float* __restrict__ hidden,     // [128][1024]
    float* __restrict__ out)              // [65536][1024]
{
    const int tid = threadIdx.x;
    const int bid = (int)blockIdx.x;
    // XCD-bijective swizzle: nwg=4096, cpx=512; 8 consecutive wgids share
    // one A m-stripe (XCD-L2/L3 reuse).
    const int wgid = (bid & 7) * 512 + (bid >> 3);
    const int nt = wgid & 7, mt = wgid >> 3;
    const int m0 = mt * 128, n0 = nt * 128;
    const int l = tid & 63, w = tid >> 6;
    const int wm = w >> 1, wn = w & 1;          // 2x2 waves, 64x64 each
    const int r = l & 15, q = l >> 4;

    // 8 scalar base pointers (kept in VGPR pairs), frag (i,T) = base + T*512
    const u16* abase = x_frag   + (size_t)(m0 / 16 + wm * 4) * 8192 + l * 8;
    const u16* bbase = Win_frag + (size_t)(n0 / 16 + wn * 4) * 8192 + l * 8;
    const u16* pa0 = abase;            const u16* pa1 = abase + 8192;
    const u16* pa2 = abase + 16384;    const u16* pa3 = abase + 24576;
    const u16* pb0 = bbase;            const u16* pb1 = bbase + 8192;
    const u16* pb2 = bbase + 16384;    const u16* pb3 = bbase + 24576;

    f32x4 acc[4][4] = {};
    bf16x8 A0[4], B0[4], A1[4], B1[4], A2[4], B2[4], A3[4], B3[4];

    // prologue: fill the 4-deep pipe (32 loads in flight)
    LD8(0, 0); LD8(1, 1); LD8(2, 2); LD8(3, 3);
    __builtin_amdgcn_sched_barrier(0);

    STEP( 0, 0, 24); STEP( 1, 1, 24); STEP( 2, 2, 24); STEP( 3, 3, 24);
    STEP( 4, 0, 24); STEP( 5, 1, 24); STEP( 6, 2, 24); STEP( 7, 3, 24);
    STEP( 8, 0, 24); STEP( 9, 1, 24); STEP(10, 2, 24); STEP(11, 3, 24);
    STEP(12, 0, 24); STEP(13, 1, 16); STEP(14, 2, 8);  STEP(15, 3, 0);

    // ---- epilogue: out = 0.9*hidden + 0.1*relu(acc + bias2), float4-wide ----
    #pragma unroll
    for (int mi = 0; mi < 4; ++mi) {
        const int m = m0 + wm * 64 + mi * 16 + r;
        const int b = m & 127;                  // m = t*128 + b
        #pragma unroll
        for (int ni = 0; ni < 4; ++ni) {
            const int n = n0 + wn * 64 + ni * 16 + q * 4;
            float4 bb = *reinterpret_cast<const float4*>(&bias2[b * 1024 + n]);
            float4 hh = *reinterpret_cast<const float4*>(&hidden[b * 1024 + n]);
            f32x4 v = acc[mi][ni];
            float4 o;
            o.x = 0.9f * hh.x + 0.1f * fmaxf(v[0] + bb.x, 0.0f);
            o.y = 0.9f * hh.y + 0.1f * fmaxf(v[1] + bb.y, 0.0f);
            o.z = 0.9f * hh.z + 0.1f * fmaxf(v[2] + bb.z, 0.0f);
            o.w = 0.9f * hh.w + 0.1f * fmaxf(v[3] + bb.w, 0.0f);
            *reinterpret_cast<float4*>(&out[(size_t)m * 1024 + n]) = o;
        }
    }
}

// ---------------------------------------------------------------------------
extern "C" void kernel_launch(void* const* d_in, const int* in_sizes, int n_in,
                              void* d_out, int out_size, void* d_ws, size_t ws_size,
                              hipStream_t stream) {
    const float* x      = (const float*)d_in[0];
    const float* hidden = (const float*)d_in[1];
    const float* W_in   = (const float*)d_in[2];
    const float* b_in   = (const float*)d_in[3];
    const float* W_h    = (const float*)d_in[4];
    const float* b_h    = (const float*)d_in[5];
    float* out = (float*)d_out;

    char* ws = (char*)d_ws;                    // ~68 MiB scratch
    u16*   x_frag   = (u16*)  (ws + 0);        // 64 MiB
    u16*   Win_frag = (u16*)  (ws + 67108864); // 1 MiB
    u16*   Wh_bf    = (u16*)  (ws + 68157440); // 2 MiB
    u16*   hid_bf   = (u16*)  (ws + 70254592); // 256 KiB
    float* bias2    = (float*)(ws + 70516736); // 512 KiB

    float* out_hidden = out + OUT_ELEMS;       // tuple output 1: hidden

    k_convert<<<16384, 256, 0, stream>>>(x, x_frag);
    k_prep<<<832, 256, 0, stream>>>(W_in, W_h, hidden,
                                    Win_frag, Wh_bf, hid_bf, out_hidden);
    k_bias2<<<32, 256, 0, stream>>>(hid_bf, Wh_bf, b_in, b_h, bias2);
    k_main<<<4096, 256, 0, stream>>>(x_frag, Win_frag, bias2, hidden, out);
}

// Round 10
// 213.979 us; speedup vs baseline: 2.2124x; 1.0664x over previous
//
#include <hip/hip_runtime.h>
#include <stdint.h>

// Problem constants
#define T_DIM 512
#define B_DIM 128
#define DIN   512
#define H_DIM 1024
#define M_DIM (T_DIM * B_DIM)          // 65536
#define OUT_ELEMS 67108864             // M_DIM * H_DIM

typedef __attribute__((ext_vector_type(8))) short bf16x8;
typedef __attribute__((ext_vector_type(4))) float f32x4;
typedef unsigned short u16;

static __device__ __forceinline__ u16 f2bf(float f) {
    union { float f; uint32_t u; } v; v.f = f;
    uint32_t u = v.u;
    uint32_t r = (u + 0x7FFFu + ((u >> 16) & 1u)) >> 16;   // RNE
    return (u16)r;
}

static __device__ __forceinline__ bf16x8 pack8(float4 v0, float4 v1) {
    union { bf16x8 v; u16 s[8]; } r;
    r.s[0] = f2bf(v0.x); r.s[1] = f2bf(v0.y);
    r.s[2] = f2bf(v0.z); r.s[3] = f2bf(v0.w);
    r.s[4] = f2bf(v1.x); r.s[5] = f2bf(v1.y);
    r.s[6] = f2bf(v1.z); r.s[7] = f2bf(v1.w);
    return r.v;
}

typedef const __attribute__((address_space(1))) void GASV;
typedef __attribute__((address_space(3))) void LASV;
static __device__ __forceinline__ void gload_lds16(const void* g, void* l) {
    __builtin_amdgcn_global_load_lds((GASV*)g, (LASV*)l, 16, 0, 0);
}

// ---------------------------------------------------------------------------
// x_frag layout, 16B chunks: [mt'=bg*64+tg][kt 0..7][f 0..7][kk2 0..1][lane]
//   lane = q*16+r ; element: t = tg*8+f, b = bg*16+r, d = kt*64+kk2*32+q*8+e
// Block (mt',nt) covers out rows {t*128+b : t in tg*8..+8, b in bg*16..+16}.
// t-major tiling => bias2/hidden depend only on r (16 b values per block):
// epilogue reads 16 KB/block instead of 128 KB.
// ---------------------------------------------------------------------------

// Kernel 0: x (f32) -> x_frag (bf16, fragment-ordered). 1 unit = 16B chunk.
__global__ __launch_bounds__(256) void k_convert(
    const float* __restrict__ x, u16* __restrict__ x_frag)
{
    int u = blockIdx.x * 256 + threadIdx.x;      // 0 .. 4194303
    int lane = u & 63, kk2 = (u >> 6) & 1, f = (u >> 7) & 7;
    int kt = (u >> 10) & 7, mtp = u >> 13;
    int bg = mtp >> 6, tg = mtp & 63;
    int r = lane & 15, q = lane >> 4;
    int t = tg * 8 + f, b = bg * 16 + r;
    int d = kt * 64 + kk2 * 32 + q * 8;
    const float* s = x + (size_t)(t * 128 + b) * 512 + d;
    float4 v0 = *reinterpret_cast<const float4*>(s);
    float4 v1 = *reinterpret_cast<const float4*>(s + 4);
    reinterpret_cast<bf16x8*>(x_frag)[u] = pack8(v0, v1);
}

// Kernel 1: W_in -> frag layout [nt][kt][f][kk2][lane]; W_h, hidden -> linear
// bf16; hidden f32 -> out tail. units: Win [0,65536) Wh [..196608) hid [..212992)
__global__ __launch_bounds__(256) void k_prep(
    const float* __restrict__ W_in, const float* __restrict__ W_h,
    const float* __restrict__ hidden,
    u16* __restrict__ Win_frag, u16* __restrict__ Wh_bf, u16* __restrict__ hid_bf,
    float* __restrict__ out_hidden)
{
    int u = blockIdx.x * 256 + threadIdx.x;
    if (u < 65536) {                              // W_in -> fragment order
        int lane = u & 63, kk2 = (u >> 6) & 1, f = (u >> 7) & 7;
        int kt = (u >> 10) & 7, nt = u >> 13;
        int r = lane & 15, q = lane >> 4;
        int n = nt * 128 + f * 16 + r;
        int d = kt * 64 + kk2 * 32 + q * 8;
        const float* s = W_in + (size_t)n * 512 + d;
        float4 v0 = *reinterpret_cast<const float4*>(s);
        float4 v1 = *reinterpret_cast<const float4*>(s + 4);
        reinterpret_cast<bf16x8*>(Win_frag)[u] = pack8(v0, v1);
    } else if (u < 196608) {                      // W_h -> linear bf16
        int i = u - 65536;
        float4 v0 = reinterpret_cast<const float4*>(W_h)[2 * (size_t)i];
        float4 v1 = reinterpret_cast<const float4*>(W_h)[2 * (size_t)i + 1];
        reinterpret_cast<bf16x8*>(Wh_bf)[i] = pack8(v0, v1);
    } else {                                      // hidden -> bf16 + copy out
        int i = u - 196608;
        float4 v0 = reinterpret_cast<const float4*>(hidden)[2 * (size_t)i];
        float4 v1 = reinterpret_cast<const float4*>(hidden)[2 * (size_t)i + 1];
        reinterpret_cast<bf16x8*>(hid_bf)[i] = pack8(v0, v1);
        reinterpret_cast<float4*>(out_hidden)[2 * i]     = v0;
        reinterpret_cast<float4*>(out_hidden)[2 * i + 1] = v1;
    }
}

// ---------------------------------------------------------------------------
// Kernel 2: bias2[b][h] = hidden @ W_h^T + b_h + b_in   (128 x 1024, K=1024)
// ---------------------------------------------------------------------------
__global__ __launch_bounds__(256, 2) void k_bias2(
    const u16* __restrict__ hid_bf, const u16* __restrict__ Wh_bf,
    const float* __restrict__ b_in, const float* __restrict__ b_h,
    float* __restrict__ bias2)
{
    __shared__ alignas(16) char lds[16384];     // A: [0,8192) B: [8192,16384)
    const int tid = threadIdx.x;
    const int mt = blockIdx.x & 1, nt = blockIdx.x >> 1;   // 2 x 16 tiles
    const int m0 = mt * 64, n0 = nt * 64;
    const int l = tid & 63, w = tid >> 6;
    const int wm = w >> 1, wn = w & 1;
    const int r = l & 15, q = l >> 4;

    f32x4 acc[2][2] = {};

    for (int kb = 0; kb < 1024; kb += 64) {
        __syncthreads();
        #pragma unroll
        for (int i = 0; i < 2; ++i) {
            int idx = tid + i * 256;            // 0..511 : 64 rows x 8 chunks
            int row = idx >> 3, koff = (idx & 7) * 8;
            int off = (row * 128 + koff * 2) ^ ((row & 7) << 4);
            bf16x8 av = *reinterpret_cast<const bf16x8*>(&hid_bf[(m0 + row) * 1024 + kb + koff]);
            *reinterpret_cast<bf16x8*>(&lds[off]) = av;
            bf16x8 bv = *reinterpret_cast<const bf16x8*>(&Wh_bf[(n0 + row) * 1024 + kb + koff]);
            *reinterpret_cast<bf16x8*>(&lds[8192 + off]) = bv;
        }
        __syncthreads();
        #pragma unroll
        for (int kk = 0; kk < 2; ++kk) {
            bf16x8 a[2], b[2];
            #pragma unroll
            for (int mi = 0; mi < 2; ++mi) {
                int row = wm * 32 + mi * 16 + r;
                int off = (row * 128 + kk * 64 + q * 16) ^ ((row & 7) << 4);
                a[mi] = *reinterpret_cast<const bf16x8*>(&lds[off]);
            }
            #pragma unroll
            for (int ni = 0; ni < 2; ++ni) {
                int row = wn * 32 + ni * 16 + r;
                int off = 8192 + ((row * 128 + kk * 64 + q * 16) ^ ((row & 7) << 4));
                b[ni] = *reinterpret_cast<const bf16x8*>(&lds[off]);
            }
            #pragma unroll
            for (int mi = 0; mi < 2; ++mi)
                #pragma unroll
                for (int ni = 0; ni < 2; ++ni)
                    acc[mi][ni] = __builtin_amdgcn_mfma_f32_16x16x32_bf16(
                        a[mi], b[ni], acc[mi][ni], 0, 0, 0);
        }
    }
    #pragma unroll
    for (int mi = 0; mi < 2; ++mi)
        #pragma unroll
        for (int ni = 0; ni < 2; ++ni)
            #pragma unroll
            for (int reg = 0; reg < 4; ++reg) {
                int brow = m0 + wm * 32 + mi * 16 + q * 4 + reg;
                int col  = n0 + wn * 32 + ni * 16 + r;
                bias2[brow * 1024 + col] = acc[mi][ni][reg] + b_in[col] + b_h[col];
            }
}

// ---------------------------------------------------------------------------
// Kernel 3: main GEMM — r3 skeleton (stage -> sync -> MFMA -> sync), but:
//   * operands pre-arranged in MFMA fragment order -> staging is a pure
//     LINEAR 16 KB memcpy (gload_lds16), no swizzle; ds_read at lane*16B
//     is conflict-free by construction.
//   * t-major block tile (16 b x 8 t rows): bias2/hidden read once per ni,
//     reused across all mi -> 16 KB epilogue reads/block (was 128 KB).
// ---------------------------------------------------------------------------
__global__ __launch_bounds__(256, 3) void k_main(
    const u16* __restrict__ x_frag,       // [512][8][8][2][64][8] bf16
    const u16* __restrict__ Win_frag,     // [8][8][8][2][64][8] bf16
    const float* __restrict__ bias2,      // [128][1024]
    const float* __restrict__ hidden,     // [128][1024]
    float* __restrict__ out)              // [65536][1024]
{
    __shared__ alignas(16) char ldsA[16384];
    __shared__ alignas(16) char ldsB[16384];

    const int tid = threadIdx.x;
    const int bid = (int)blockIdx.x;
    // XCD-bijective swizzle: nwg=4096, cpx=512; 8 consecutive wgids share
    // one A m-stripe (XCD-L2 reuse).
    const int wgid = (bid & 7) * 512 + (bid >> 3);
    const int nt = wgid & 7, mtp = wgid >> 3;   // n-tile, m-tile'
    const int bg = mtp >> 6, tg = mtp & 63;     // 16-b group, 8-t group
    const int l = tid & 63, w = tid >> 6;
    const int wm = w >> 1, wn = w & 1;          // 2x2 waves, 64x64 each
    const int r = l & 15, q = l >> 4;

    const char* asrc = (const char*)x_frag   + (size_t)mtp * 131072;  // 8 kt x 16 KB
    const char* bsrc = (const char*)Win_frag + (size_t)nt  * 131072;

    f32x4 acc[4][4] = {};

    for (int kt = 0; kt < 8; ++kt) {
        // ---- stage: linear 16 KB memcpy each for A and B ----
        #pragma unroll
        for (int i = 0; i < 4; ++i) {
            const int off = tid * 16 + i * 4096;
            gload_lds16(asrc + kt * 16384 + off, &ldsA[off]);
            gload_lds16(bsrc + kt * 16384 + off, &ldsB[off]);
        }
        __syncthreads();   // drains vmcnt(0): tiles resident

        #pragma unroll
        for (int kk2 = 0; kk2 < 2; ++kk2) {
            bf16x8 a[4], b[4];
            #pragma unroll
            for (int mi = 0; mi < 4; ++mi)
                a[mi] = *reinterpret_cast<const bf16x8*>(
                    &ldsA[(wm * 4 + mi) * 2048 + kk2 * 1024 + l * 16]);
            #pragma unroll
            for (int ni = 0; ni < 4; ++ni)
                b[ni] = *reinterpret_cast<const bf16x8*>(
                    &ldsB[(wn * 4 + ni) * 2048 + kk2 * 1024 + l * 16]);
            // swapped operands: lane (q,r): out-row = a-row(r), regs = 4 n
            #pragma unroll
            for (int mi = 0; mi < 4; ++mi)
                #pragma unroll
                for (int ni = 0; ni < 4; ++ni)
                    acc[mi][ni] = __builtin_amdgcn_mfma_f32_16x16x32_bf16(
                        b[ni], a[mi], acc[mi][ni], 0, 0, 0);
        }
        __syncthreads();   // protect LDS before next kt's staging
    }

    // ---- epilogue: bias2/hidden shared across mi (same b for whole wave) ----
    const int b = bg * 16 + r;                  // lane's batch index
    float4 bb[4], hh[4];
    #pragma unroll
    for (int ni = 0; ni < 4; ++ni) {
        const int n = nt * 128 + wn * 64 + ni * 16 + q * 4;
        bb[ni] = *reinterpret_cast<const float4*>(&bias2[b * 1024 + n]);
        hh[ni] = *reinterpret_cast<const float4*>(&hidden[b * 1024 + n]);
    }
    #pragma unroll
    for (int mi = 0; mi < 4; ++mi) {
        const int t = tg * 8 + wm * 4 + mi;
        float* orow = out + (size_t)(t * 128 + b) * 1024;
        #pragma unroll
        for (int ni = 0; ni < 4; ++ni) {
            const int n = nt * 128 + wn * 64 + ni * 16 + q * 4;
            f32x4 v = acc[mi][ni];
            float4 o;
            o.x = 0.9f * hh[ni].x + 0.1f * fmaxf(v[0] + bb[ni].x, 0.0f);
            o.y = 0.9f * hh[ni].y + 0.1f * fmaxf(v[1] + bb[ni].y, 0.0f);
            o.z = 0.9f * hh[ni].z + 0.1f * fmaxf(v[2] + bb[ni].z, 0.0f);
            o.w = 0.9f * hh[ni].w + 0.1f * fmaxf(v[3] + bb[ni].w, 0.0f);
            *reinterpret_cast<float4*>(orow + n) = o;
        }
    }
}

// ---------------------------------------------------------------------------
extern "C" void kernel_launch(void* const* d_in, const int* in_sizes, int n_in,
                              void* d_out, int out_size, void* d_ws, size_t ws_size,
                              hipStream_t stream) {
    const float* x      = (const float*)d_in[0];
    const float* hidden = (const float*)d_in[1];
    const float* W_in   = (const float*)d_in[2];
    const float* b_in   = (const float*)d_in[3];
    const float* W_h    = (const float*)d_in[4];
    const float* b_h    = (const float*)d_in[5];
    float* out = (float*)d_out;

    char* ws = (char*)d_ws;                    // ~68 MiB scratch
    u16*   x_frag   = (u16*)  (ws + 0);        // 64 MiB
    u16*   Win_frag = (u16*)  (ws + 67108864); // 1 MiB
    u16*   Wh_bf    = (u16*)  (ws + 68157440); // 2 MiB
    u16*   hid_bf   = (u16*)  (ws + 70254592); // 256 KiB
    float* bias2    = (float*)(ws + 70516736); // 512 KiB

    float* out_hidden = out + OUT_ELEMS;       // tuple output 1: hidden

    k_convert<<<16384, 256, 0, stream>>>(x, x_frag);
    k_prep<<<832, 256, 0, stream>>>(W_in, W_h, hidden,
                                    Win_frag, Wh_bf, hid_bf, out_hidden);
    k_bias2<<<32, 256, 0, stream>>>(hid_bf, Wh_bf, b_in, b_h, bias2);
    k_main<<<4096, 256, 0, stream>>>(x_frag, Win_frag, bias2, hidden, out);
}